// Round 3
// baseline (904.053 us; speedup 1.0000x reference)
//
#include <hip/hip_runtime.h>

// SIGN model: N=50000, E=800000, CIN=64, HOPS=3, HID=256, COUT=64
// z layout: [N, 256] row-major; col-block k (64 wide) = hop-k embedding (k=0 is x).
// SPMM via on-device CSR grouped by destination (col): no float atomics.
// MLP: fp32 VALU GEMMs, BM=64 x BN=256 (A read once), layer1+2 fused.

#define ZW 256
#define NCH 64

// z[:,0:64] = x; deg = 0.
__global__ void init_kernel(const float* __restrict__ x, float* __restrict__ z,
                            int* __restrict__ deg, int N) {
    int stride = gridDim.x * blockDim.x;
    int total4 = N * (NCH / 4);
    for (int idx = blockIdx.x * blockDim.x + threadIdx.x; idx < total4; idx += stride) {
        int n = idx >> 4;
        int c4 = idx & 15;
        reinterpret_cast<float4*>(z + (size_t)n * ZW)[c4] =
            reinterpret_cast<const float4*>(x + (size_t)n * NCH)[c4];
    }
    for (int idx = blockIdx.x * blockDim.x + threadIdx.x; idx < N; idx += stride)
        deg[idx] = 0;
}

__global__ void degree_kernel(const int* __restrict__ col, int* __restrict__ deg, int E) {
    int stride = gridDim.x * blockDim.x;
    for (int e = blockIdx.x * blockDim.x + threadIdx.x; e < E; e += stride)
        atomicAdd(&deg[col[e]], 1);
}

// Two-level scan: per-block inclusive scan + block sums.
__global__ __launch_bounds__(1024) void scan_part_kernel(const int* __restrict__ deg,
                                                         int* __restrict__ off,
                                                         int* __restrict__ bsum, int N) {
    __shared__ int smem[1024];
    int tid = threadIdx.x;
    int i = blockIdx.x * 1024 + tid;
    int v = (i < N) ? deg[i] : 0;
    smem[tid] = v;
    __syncthreads();
    for (int o = 1; o < 1024; o <<= 1) {
        int t = (tid >= o) ? smem[tid - o] : 0;
        __syncthreads();
        smem[tid] += t;
        __syncthreads();
    }
    if (i < N) off[i] = smem[tid] - v;   // block-local exclusive
    if (tid == 1023) bsum[blockIdx.x] = smem[1023];
}

// Scan the (<=64) block sums with one wave.
__global__ void scan_tops_kernel(const int* __restrict__ bsum, int* __restrict__ btot, int nb) {
    int lane = threadIdx.x;
    int v = (lane < nb) ? bsum[lane] : 0;
    int incl = v;
    for (int o = 1; o < 64; o <<= 1) {
        int t = __shfl_up(incl, o);
        if (lane >= o) incl += t;
    }
    if (lane < nb) btot[lane] = incl - v;
    if (lane == 63) btot[nb] = incl;     // total
}

__global__ __launch_bounds__(1024) void scan_add_kernel(int* __restrict__ off,
                                                        int* __restrict__ cur,
                                                        const int* __restrict__ btot,
                                                        int N, int nb) {
    int i = blockIdx.x * 1024 + threadIdx.x;
    if (i < N) {
        int o = off[i] + btot[blockIdx.x];
        off[i] = o;
        cur[i] = o;
    }
    if (i == 0) off[N] = btot[nb];
}

// Scatter edges into CSR slots; edge value computed inline.
__global__ void scatter_kernel(const int* __restrict__ row, const int* __restrict__ col,
                               const int* __restrict__ deg, int* __restrict__ cursor,
                               int2* __restrict__ meta, int E) {
    int stride = gridDim.x * blockDim.x;
    for (int e = blockIdx.x * blockDim.x + threadIdx.x; e < E; e += stride) {
        int r = row[e];
        int c = col[e];
        int dc = deg[c];
        int dr = deg[r];
        float v = 0.0f;
        if (dc > 0 && dr > 0) v = rsqrtf((float)(dc * dr));
        int pos = atomicAdd(&cursor[c], 1);
        meta[pos] = make_int2(r, __float_as_int(v));
    }
}

// One wave per destination node; lane = channel. No atomics: single coalesced store.
__global__ void spmm_csr_kernel(const int* __restrict__ offsets, const int2* __restrict__ meta,
                                const float* __restrict__ zin, float* __restrict__ zout, int N) {
    int lane = threadIdx.x & 63;
    int wave = (blockIdx.x * blockDim.x + threadIdx.x) >> 6;
    if (wave >= N) return;
    int start = offsets[wave];
    int end   = offsets[wave + 1];
    float acc = 0.0f;
    int j = start;
    for (; j + 2 <= end; j += 2) {
        int2 m0 = meta[j];
        int2 m1 = meta[j + 1];
        float h0 = zin[(size_t)m0.x * ZW + lane];
        float h1 = zin[(size_t)m1.x * ZW + lane];
        acc = fmaf(__int_as_float(m0.y), h0, acc);
        acc = fmaf(__int_as_float(m1.y), h1, acc);
    }
    if (j < end) {
        int2 m0 = meta[j];
        acc = fmaf(__int_as_float(m0.y), zin[(size_t)m0.x * ZW + lane], acc);
    }
    zout[(size_t)wave * ZW + lane] = acc;
}

// ---------------- GEMM: C[M,256] = relu(A[M,256] @ W[256,256] + b) -----------------
// BM=64, BN=256 (full width: A read once), BK=32, 256 threads, 8x8 per thread.
#define BKK 32

struct P1 {
    float As[64][36];      // [m][k] row-major, broadcast reads
    float Ws[BKK][260];    // [k][n]
};

template <typename SM>
__device__ __forceinline__ void gemm_mainloop(const float* __restrict__ A,
                                              const float* __restrict__ W,
                                              SM* sm, float acc[8][8], int bm, int M) {
    int tid = threadIdx.x;
    int tx = tid & 31, ty = tid >> 5;
    int arow = tid >> 2, akq = (tid & 3) * 8;
    int grow = bm + arow;
    bool avalid = grow < M;
    const float* Arow = A + (size_t)grow * 256 + akq;

    for (int k0 = 0; k0 < 256; k0 += BKK) {
        float4 a0 = make_float4(0.f, 0.f, 0.f, 0.f), a1 = a0;
        if (avalid) {
            a0 = *reinterpret_cast<const float4*>(Arow + k0);
            a1 = *reinterpret_cast<const float4*>(Arow + k0 + 4);
        }
        *reinterpret_cast<float4*>(&sm->As[arow][akq])     = a0;
        *reinterpret_cast<float4*>(&sm->As[arow][akq + 4]) = a1;

#pragma unroll
        for (int j = 0; j < 8; ++j) {
            int idx4 = j * 256 + tid;
            int wk = idx4 >> 6;
            int wc = (idx4 & 63) << 2;
            *reinterpret_cast<float4*>(&sm->Ws[wk][wc]) =
                *reinterpret_cast<const float4*>(W + (size_t)(k0 + wk) * 256 + wc);
        }
        __syncthreads();

#pragma unroll
        for (int kk = 0; kk < BKK; ++kk) {
            float4 w0 = *reinterpret_cast<const float4*>(&sm->Ws[kk][tx * 8]);
            float4 w1 = *reinterpret_cast<const float4*>(&sm->Ws[kk][tx * 8 + 4]);
            float wv[8] = {w0.x, w0.y, w0.z, w0.w, w1.x, w1.y, w1.z, w1.w};
#pragma unroll
            for (int i = 0; i < 8; ++i) {
                float a = sm->As[ty * 8 + i][kk];
#pragma unroll
                for (int j = 0; j < 8; ++j) acc[i][j] = fmaf(a, wv[j], acc[i][j]);
            }
        }
        __syncthreads();
    }
}

__global__ __launch_bounds__(256) void gemm_l0_kernel(const float* __restrict__ A,
                                                      const float* __restrict__ W,
                                                      const float* __restrict__ bias,
                                                      float* __restrict__ C, int M) {
    __shared__ P1 sm;
    int tid = threadIdx.x;
    int tx = tid & 31, ty = tid >> 5;
    int bm = blockIdx.x * 64;
    float acc[8][8] = {};
    gemm_mainloop(A, W, &sm, acc, bm, M);

    float4 b0 = *reinterpret_cast<const float4*>(bias + tx * 8);
    float4 b1 = *reinterpret_cast<const float4*>(bias + tx * 8 + 4);
    float bv[8] = {b0.x, b0.y, b0.z, b0.w, b1.x, b1.y, b1.z, b1.w};
#pragma unroll
    for (int i = 0; i < 8; ++i) {
        int gr = bm + ty * 8 + i;
        if (gr >= M) continue;
        float o[8];
#pragma unroll
        for (int j = 0; j < 8; ++j) o[j] = fmaxf(acc[i][j] + bv[j], 0.0f);
        *reinterpret_cast<float4*>(C + (size_t)gr * 256 + tx * 8)     = make_float4(o[0], o[1], o[2], o[3]);
        *reinterpret_cast<float4*>(C + (size_t)gr * 256 + tx * 8 + 4) = make_float4(o[4], o[5], o[6], o[7]);
    }
}

// Fused layer1+layer2: h = relu(A@W1+b1) (64x256 tile in LDS), out = h@W2 + b2.
union SMF {
    P1 p1;
    float hs[64][260];
};

__global__ __launch_bounds__(256, 2) void gemm_l12_kernel(const float* __restrict__ A,
                                                          const float* __restrict__ W1,
                                                          const float* __restrict__ b1,
                                                          const float* __restrict__ W2,
                                                          const float* __restrict__ b2,
                                                          float* __restrict__ out, int M) {
    __shared__ SMF sm;
    int tid = threadIdx.x;
    int tx = tid & 31, ty = tid >> 5;
    int bm = blockIdx.x * 64;
    float acc[8][8] = {};
    gemm_mainloop(A, W1, &sm.p1, acc, bm, M);

    // h tile -> LDS (with bias+relu). Union safe: all threads past final sync.
    float4 c0 = *reinterpret_cast<const float4*>(b1 + tx * 8);
    float4 c1 = *reinterpret_cast<const float4*>(b1 + tx * 8 + 4);
    float bv[8] = {c0.x, c0.y, c0.z, c0.w, c1.x, c1.y, c1.z, c1.w};
#pragma unroll
    for (int i = 0; i < 8; ++i) {
        float o[8];
#pragma unroll
        for (int j = 0; j < 8; ++j) o[j] = fmaxf(acc[i][j] + bv[j], 0.0f);
        *reinterpret_cast<float4*>(&sm.hs[ty * 8 + i][tx * 8])     = make_float4(o[0], o[1], o[2], o[3]);
        *reinterpret_cast<float4*>(&sm.hs[ty * 8 + i][tx * 8 + 4]) = make_float4(o[4], o[5], o[6], o[7]);
    }
    __syncthreads();

    // Phase 2: out[64x64] = h[64x256] @ W2[256x64] + b2. 4x4 per thread.
    int tx2 = tid & 15, ty2 = tid >> 4;
    float acc2[4][4] = {};
#pragma unroll 4
    for (int k = 0; k < 256; ++k) {
        float4 w2 = *reinterpret_cast<const float4*>(W2 + (size_t)k * 64 + tx2 * 4);
        float wv2[4] = {w2.x, w2.y, w2.z, w2.w};
#pragma unroll
        for (int i = 0; i < 4; ++i) {
            float h = sm.hs[ty2 * 4 + i][k];
#pragma unroll
            for (int j = 0; j < 4; ++j) acc2[i][j] = fmaf(h, wv2[j], acc2[i][j]);
        }
    }
    float4 bb = *reinterpret_cast<const float4*>(b2 + tx2 * 4);
    float bv2[4] = {bb.x, bb.y, bb.z, bb.w};
#pragma unroll
    for (int i = 0; i < 4; ++i) {
        int gr = bm + ty2 * 4 + i;
        if (gr >= M) continue;
        float o[4];
#pragma unroll
        for (int j = 0; j < 4; ++j) o[j] = acc2[i][j] + bv2[j];
        *reinterpret_cast<float4*>(out + (size_t)gr * 64 + tx2 * 4) = make_float4(o[0], o[1], o[2], o[3]);
    }
}

extern "C" void kernel_launch(void* const* d_in, const int* in_sizes, int n_in,
                              void* d_out, int out_size, void* d_ws, size_t ws_size,
                              hipStream_t stream) {
    const float* x  = (const float*)d_in[0];
    const int* ei   = (const int*)d_in[1];
    const float* W0 = (const float*)d_in[2];
    const float* b0 = (const float*)d_in[3];
    const float* W1 = (const float*)d_in[4];
    const float* b1 = (const float*)d_in[5];
    const float* W2 = (const float*)d_in[6];
    const float* b2 = (const float*)d_in[7];
    float* out = (float*)d_out;

    const int N = in_sizes[0] / NCH;      // 50000
    const int E = in_sizes[1] / 2;        // 800000
    const int* row = ei;
    const int* col = ei + E;

    // workspace layout
    float* z   = (float*)d_ws;                 // N*256 f
    float* zt  = z + (size_t)N * ZW;           // N*256 f
    int*   deg = (int*)(zt + (size_t)N * ZW);  // N
    int*   off = deg + N;                      // N+1
    int*   cur = off + N + 1;                  // N
    int*   bsum = cur + N;                     // 64
    int*   btot = bsum + 64;                   // 65
    int2*  meta = (int2*)zt;                   // E int2, overlays zt (disjoint lifetime)

    const int TB = 256;
    const int NB = (N + 1023) / 1024;          // 49

    init_kernel<<<2048, TB, 0, stream>>>(x, z, deg, N);
    degree_kernel<<<1024, TB, 0, stream>>>(col, deg, E);
    scan_part_kernel<<<NB, 1024, 0, stream>>>(deg, off, bsum, N);
    scan_tops_kernel<<<1, 64, 0, stream>>>(bsum, btot, NB);
    scan_add_kernel<<<NB, 1024, 0, stream>>>(off, cur, btot, N, NB);
    scatter_kernel<<<1024, TB, 0, stream>>>(row, col, deg, cur, meta, E);

    int spmm_blocks = (N * 64 + TB - 1) / TB;
    for (int hop = 1; hop <= 3; ++hop) {
        const float* zin = z + (hop - 1) * NCH;
        float* zout      = z + hop * NCH;
        spmm_csr_kernel<<<spmm_blocks, TB, 0, stream>>>(off, meta, zin, zout, N);
    }

    int gblocks = (N + 63) / 64;               // 782
    gemm_l0_kernel<<<gblocks, TB, 0, stream>>>(z, W0, b0, zt, N);
    gemm_l12_kernel<<<gblocks, TB, 0, stream>>>(zt, W1, b1, W2, b2, out, N);
}

// Round 4
// 430.419 us; speedup vs baseline: 2.1004x; 2.1004x over previous
//
#include <hip/hip_runtime.h>

// SIGN: N=50000, E=800000, CIN=64, HOPS=3, HID=256, COUT=64
// z stored PACKED: u32 = (bf16_hi << 16) | bf16_lo, value = hi + lo (~fp32 to 2^-18).
// SPMM: CSR-by-destination, no float atomics. MLP: split-bf16 MFMA GEMMs.

#define ZW 256
#define NCH 64

typedef __attribute__((ext_vector_type(8))) __bf16 bf16x8;
typedef __attribute__((ext_vector_type(4))) float f32x4;
typedef __attribute__((ext_vector_type(4))) unsigned short us4;

__device__ __forceinline__ unsigned f2bf(float f) {
    unsigned x = __float_as_uint(f);
    return (x + 0x7fffu + ((x >> 16) & 1u)) >> 16;   // RNE, finite inputs
}
__device__ __forceinline__ unsigned pack_split(float v) {
    unsigned hb = f2bf(v);
    float hf = __uint_as_float(hb << 16);
    unsigned lb = f2bf(v - hf);
    return (hb << 16) | lb;
}
__device__ __forceinline__ float unpack_f(unsigned u) {
    return __uint_as_float(u & 0xffff0000u) + __uint_as_float(u << 16);
}

// ---------------- prologue ----------------

__global__ void init_kernel(const float* __restrict__ x, unsigned* __restrict__ zp,
                            int* __restrict__ deg, int N) {
    int stride = gridDim.x * blockDim.x;
    int total4 = N * 16;
    for (int idx = blockIdx.x * blockDim.x + threadIdx.x; idx < total4; idx += stride) {
        int n = idx >> 4, c4 = idx & 15;
        float4 v = *reinterpret_cast<const float4*>(x + (size_t)n * NCH + c4 * 4);
        uint4 o;
        o.x = pack_split(v.x); o.y = pack_split(v.y);
        o.z = pack_split(v.z); o.w = pack_split(v.w);
        *reinterpret_cast<uint4*>(zp + (size_t)n * ZW + c4 * 4) = o;
    }
    for (int idx = blockIdx.x * blockDim.x + threadIdx.x; idx < N; idx += stride)
        deg[idx] = 0;
}

__global__ void degree_kernel(const int* __restrict__ col, int* __restrict__ deg, int E) {
    int stride = gridDim.x * blockDim.x;
    for (int e = blockIdx.x * blockDim.x + threadIdx.x; e < E; e += stride)
        atomicAdd(&deg[col[e]], 1);
}

__global__ __launch_bounds__(1024) void scan_part_kernel(const int* __restrict__ deg,
                                                         int* __restrict__ off,
                                                         int* __restrict__ bsum, int N) {
    __shared__ int smem[1024];
    int tid = threadIdx.x;
    int i = blockIdx.x * 1024 + tid;
    int v = (i < N) ? deg[i] : 0;
    smem[tid] = v;
    __syncthreads();
    for (int o = 1; o < 1024; o <<= 1) {
        int t = (tid >= o) ? smem[tid - o] : 0;
        __syncthreads();
        smem[tid] += t;
        __syncthreads();
    }
    if (i < N) off[i] = smem[tid] - v;
    if (tid == 1023) bsum[blockIdx.x] = smem[1023];
}

__global__ void scan_tops_kernel(const int* __restrict__ bsum, int* __restrict__ btot, int nb) {
    int lane = threadIdx.x;
    int v = (lane < nb) ? bsum[lane] : 0;
    int incl = v;
    for (int o = 1; o < 64; o <<= 1) {
        int t = __shfl_up(incl, o);
        if (lane >= o) incl += t;
    }
    if (lane < nb) btot[lane] = incl - v;
    if (lane == 63) btot[nb] = incl;
}

__global__ __launch_bounds__(1024) void scan_add_kernel(int* __restrict__ off,
                                                        int* __restrict__ cur,
                                                        const int* __restrict__ btot,
                                                        int N, int nb) {
    int i = blockIdx.x * 1024 + threadIdx.x;
    if (i < N) {
        int o = off[i] + btot[blockIdx.x];
        off[i] = o;
        cur[i] = o;
    }
    if (i == 0) off[N] = btot[nb];
}

__global__ void scatter_kernel(const int* __restrict__ row, const int* __restrict__ col,
                               const int* __restrict__ deg, int* __restrict__ cursor,
                               int2* __restrict__ meta, int E) {
    int stride = gridDim.x * blockDim.x;
    for (int e = blockIdx.x * blockDim.x + threadIdx.x; e < E; e += stride) {
        int r = row[e];
        int c = col[e];
        int dc = deg[c];
        int dr = deg[r];
        float v = 0.0f;
        if (dc > 0 && dr > 0) v = rsqrtf((float)(dc * dr));
        int pos = atomicAdd(&cursor[c], 1);
        meta[pos] = make_int2(r, __float_as_int(v));
    }
}

// One wave per destination node; lane = channel. Packed gather + packed store.
__global__ void spmm_csr_kernel(const int* __restrict__ offsets, const int2* __restrict__ meta,
                                const unsigned* __restrict__ zin, unsigned* __restrict__ zout,
                                int N) {
    int lane = threadIdx.x & 63;
    int wave = (blockIdx.x * blockDim.x + threadIdx.x) >> 6;
    if (wave >= N) return;
    int start = offsets[wave];
    int end   = offsets[wave + 1];
    float acc = 0.0f;
    int j = start;
    for (; j + 2 <= end; j += 2) {
        int2 m0 = meta[j];
        int2 m1 = meta[j + 1];
        float h0 = unpack_f(zin[(size_t)m0.x * ZW + lane]);
        float h1 = unpack_f(zin[(size_t)m1.x * ZW + lane]);
        acc = fmaf(__int_as_float(m0.y), h0, acc);
        acc = fmaf(__int_as_float(m1.y), h1, acc);
    }
    if (j < end) {
        int2 m0 = meta[j];
        acc = fmaf(__int_as_float(m0.y), unpack_f(zin[(size_t)m0.x * ZW + lane]), acc);
    }
    zout[(size_t)wave * ZW + lane] = pack_split(acc);
}

// Split + transpose weights: W[k][n] fp32 -> Wh/Wl[n][k] bf16 (ushort bits).
// ws layout (ushort idx): W0h 0, W0l 65536, W1h 131072, W1l 196608, W2h 262144, W2l 278528.
__global__ void prep_w_kernel(const float* __restrict__ W0, const float* __restrict__ W1,
                              const float* __restrict__ W2, unsigned short* __restrict__ ws) {
    int idx = blockIdx.x * blockDim.x + threadIdx.x;
    if (idx >= 65536) return;
    int n = idx >> 8, k = idx & 255;
    unsigned p0 = pack_split(W0[(size_t)k * 256 + n]);
    ws[idx]          = (unsigned short)(p0 >> 16);
    ws[65536 + idx]  = (unsigned short)(p0 & 0xffff);
    unsigned p1 = pack_split(W1[(size_t)k * 256 + n]);
    ws[131072 + idx] = (unsigned short)(p1 >> 16);
    ws[196608 + idx] = (unsigned short)(p1 & 0xffff);
    if (idx < 16384) {
        int n2 = idx >> 8, k2 = idx & 255;       // n2 in [0,64)
        unsigned p2 = pack_split(W2[(size_t)k2 * 64 + n2]);
        ws[262144 + idx] = (unsigned short)(p2 >> 16);
        ws[278528 + idx] = (unsigned short)(p2 & 0xffff);
    }
}

// ------------- split-bf16 MFMA GEMM: C[M,256] = relu(A@W + b), packed in/out -------------
// BM=128, BN=128, BK=32; 4 waves (2x2), wave tile 64x64 = 4x4 16x16 frags; 3 MFMA per frag pair.
__global__ __launch_bounds__(256) void gemm256_kernel(
        const unsigned* __restrict__ Ap, const unsigned short* __restrict__ Wh,
        const unsigned short* __restrict__ Wl, const float* __restrict__ bias,
        unsigned* __restrict__ Cp, int M) {
    __shared__ unsigned short Ah[128][40];
    __shared__ unsigned short Al[128][40];
    __shared__ unsigned short Bh[128][40];
    __shared__ unsigned short Bl[128][40];

    int tid = threadIdx.x;
    int lane = tid & 63;
    int wid = tid >> 6;
    int wr = wid >> 1, wc = wid & 1;
    int bm = blockIdx.x * 128;
    int bn = blockIdx.y * 128;
    int l15 = lane & 15, kg = lane >> 4;

    f32x4 acc[4][4] = {};

    for (int k0 = 0; k0 < 256; k0 += 32) {
        // stage A (packed -> hi/lo LDS), 128x32 u32
#pragma unroll
        for (int it = 0; it < 4; ++it) {
            int idx = it * 256 + tid;
            int row = idx >> 3, ch = idx & 7;
            int grow = bm + row; if (grow > M - 1) grow = M - 1;
            uint4 q = *reinterpret_cast<const uint4*>(Ap + (size_t)grow * 256 + k0 + ch * 4);
            us4 hi, lo;
            hi.x = (unsigned short)(q.x >> 16); lo.x = (unsigned short)q.x;
            hi.y = (unsigned short)(q.y >> 16); lo.y = (unsigned short)q.y;
            hi.z = (unsigned short)(q.z >> 16); lo.z = (unsigned short)q.z;
            hi.w = (unsigned short)(q.w >> 16); lo.w = (unsigned short)q.w;
            *reinterpret_cast<us4*>(&Ah[row][ch * 4]) = hi;
            *reinterpret_cast<us4*>(&Al[row][ch * 4]) = lo;
        }
        // stage B from pre-transposed [n][k] bf16
#pragma unroll
        for (int it = 0; it < 2; ++it) {
            int idx = it * 256 + tid;
            int n = idx >> 2, ch = idx & 3;
            *reinterpret_cast<uint4*>(&Bh[n][ch * 8]) =
                *reinterpret_cast<const uint4*>(Wh + (size_t)(bn + n) * 256 + k0 + ch * 8);
            *reinterpret_cast<uint4*>(&Bl[n][ch * 8]) =
                *reinterpret_cast<const uint4*>(Wl + (size_t)(bn + n) * 256 + k0 + ch * 8);
        }
        __syncthreads();

        bf16x8 ah[4], al[4], bh[4], bl[4];
#pragma unroll
        for (int m = 0; m < 4; ++m) {
            int r = wr * 64 + m * 16 + l15;
            ah[m] = *reinterpret_cast<const bf16x8*>(&Ah[r][kg * 8]);
            al[m] = *reinterpret_cast<const bf16x8*>(&Al[r][kg * 8]);
        }
#pragma unroll
        for (int n = 0; n < 4; ++n) {
            int c = wc * 64 + n * 16 + l15;
            bh[n] = *reinterpret_cast<const bf16x8*>(&Bh[c][kg * 8]);
            bl[n] = *reinterpret_cast<const bf16x8*>(&Bl[c][kg * 8]);
        }
#pragma unroll
        for (int m = 0; m < 4; ++m)
#pragma unroll
            for (int n = 0; n < 4; ++n) {
                acc[m][n] = __builtin_amdgcn_mfma_f32_16x16x32_bf16(ah[m], bh[n], acc[m][n], 0, 0, 0);
                acc[m][n] = __builtin_amdgcn_mfma_f32_16x16x32_bf16(ah[m], bl[n], acc[m][n], 0, 0, 0);
                acc[m][n] = __builtin_amdgcn_mfma_f32_16x16x32_bf16(al[m], bh[n], acc[m][n], 0, 0, 0);
            }
        __syncthreads();
    }

    // epilogue: C row = (lane>>4)*4 + reg, col = lane&15  [m89]
#pragma unroll
    for (int n = 0; n < 4; ++n) {
        int col = bn + wc * 64 + n * 16 + l15;
        float bv = bias[col];
#pragma unroll
        for (int m = 0; m < 4; ++m) {
#pragma unroll
            for (int r = 0; r < 4; ++r) {
                int row = bm + wr * 64 + m * 16 + kg * 4 + r;
                if (row < M) {
                    float v = fmaxf(acc[m][n][r] + bv, 0.0f);
                    Cp[(size_t)row * 256 + col] = pack_split(v);
                }
            }
        }
    }
}

// Final layer: out[M,64] = A@W2 + b2 (fp32 out). BM=128, 4 waves stacked, wave tile 32x64.
__global__ __launch_bounds__(256) void gemm64_kernel(
        const unsigned* __restrict__ Ap, const unsigned short* __restrict__ Wh,
        const unsigned short* __restrict__ Wl, const float* __restrict__ bias,
        float* __restrict__ out, int M) {
    __shared__ unsigned short Ah[128][40];
    __shared__ unsigned short Al[128][40];
    __shared__ unsigned short Bh[64][40];
    __shared__ unsigned short Bl[64][40];

    int tid = threadIdx.x;
    int lane = tid & 63;
    int wid = tid >> 6;
    int bm = blockIdx.x * 128;
    int l15 = lane & 15, kg = lane >> 4;

    f32x4 acc[2][4] = {};

    for (int k0 = 0; k0 < 256; k0 += 32) {
#pragma unroll
        for (int it = 0; it < 4; ++it) {
            int idx = it * 256 + tid;
            int row = idx >> 3, ch = idx & 7;
            int grow = bm + row; if (grow > M - 1) grow = M - 1;
            uint4 q = *reinterpret_cast<const uint4*>(Ap + (size_t)grow * 256 + k0 + ch * 4);
            us4 hi, lo;
            hi.x = (unsigned short)(q.x >> 16); lo.x = (unsigned short)q.x;
            hi.y = (unsigned short)(q.y >> 16); lo.y = (unsigned short)q.y;
            hi.z = (unsigned short)(q.z >> 16); lo.z = (unsigned short)q.z;
            hi.w = (unsigned short)(q.w >> 16); lo.w = (unsigned short)q.w;
            *reinterpret_cast<us4*>(&Ah[row][ch * 4]) = hi;
            *reinterpret_cast<us4*>(&Al[row][ch * 4]) = lo;
        }
        {
            int n = tid >> 2, ch = tid & 3;
            *reinterpret_cast<uint4*>(&Bh[n][ch * 8]) =
                *reinterpret_cast<const uint4*>(Wh + (size_t)n * 256 + k0 + ch * 8);
            *reinterpret_cast<uint4*>(&Bl[n][ch * 8]) =
                *reinterpret_cast<const uint4*>(Wl + (size_t)n * 256 + k0 + ch * 8);
        }
        __syncthreads();

        bf16x8 ah[2], al[2], bh[4], bl[4];
#pragma unroll
        for (int m = 0; m < 2; ++m) {
            int r = wid * 32 + m * 16 + l15;
            ah[m] = *reinterpret_cast<const bf16x8*>(&Ah[r][kg * 8]);
            al[m] = *reinterpret_cast<const bf16x8*>(&Al[r][kg * 8]);
        }
#pragma unroll
        for (int n = 0; n < 4; ++n) {
            int c = n * 16 + l15;
            bh[n] = *reinterpret_cast<const bf16x8*>(&Bh[c][kg * 8]);
            bl[n] = *reinterpret_cast<const bf16x8*>(&Bl[c][kg * 8]);
        }
#pragma unroll
        for (int m = 0; m < 2; ++m)
#pragma unroll
            for (int n = 0; n < 4; ++n) {
                acc[m][n] = __builtin_amdgcn_mfma_f32_16x16x32_bf16(ah[m], bh[n], acc[m][n], 0, 0, 0);
                acc[m][n] = __builtin_amdgcn_mfma_f32_16x16x32_bf16(ah[m], bl[n], acc[m][n], 0, 0, 0);
                acc[m][n] = __builtin_amdgcn_mfma_f32_16x16x32_bf16(al[m], bh[n], acc[m][n], 0, 0, 0);
            }
        __syncthreads();
    }

#pragma unroll
    for (int n = 0; n < 4; ++n) {
        int col = n * 16 + l15;
        float bv = bias[col];
#pragma unroll
        for (int m = 0; m < 2; ++m) {
#pragma unroll
            for (int r = 0; r < 4; ++r) {
                int row = bm + wid * 32 + m * 16 + kg * 4 + r;
                if (row < M) out[(size_t)row * 64 + col] = acc[m][n][r] + bv;
            }
        }
    }
}

extern "C" void kernel_launch(void* const* d_in, const int* in_sizes, int n_in,
                              void* d_out, int out_size, void* d_ws, size_t ws_size,
                              hipStream_t stream) {
    const float* x  = (const float*)d_in[0];
    const int* ei   = (const int*)d_in[1];
    const float* W0 = (const float*)d_in[2];
    const float* b0 = (const float*)d_in[3];
    const float* W1 = (const float*)d_in[4];
    const float* b1 = (const float*)d_in[5];
    const float* W2 = (const float*)d_in[6];
    const float* b2 = (const float*)d_in[7];
    float* out = (float*)d_out;

    const int N = in_sizes[0] / NCH;      // 50000
    const int E = in_sizes[1] / 2;        // 800000
    const int* row = ei;
    const int* col = ei + E;

    // workspace
    unsigned* zp = (unsigned*)d_ws;                       // N*256 u32 (packed z)
    unsigned* hp = zp + (size_t)N * ZW;                   // N*256 u32 (packed h / meta overlay)
    int* deg  = (int*)(hp + (size_t)N * ZW);              // N
    int* off  = deg + N;                                  // N+1
    int* cur  = off + N + 1;                              // N
    int* bsum = cur + N;                                  // 64
    int* btot = bsum + 64;                                // 80
    unsigned short* wsp = (unsigned short*)(btot + 80);   // 294912 ushorts (split weights)
    int2* meta = (int2*)hp;                               // overlays hp (disjoint lifetime)

    const int TB = 256;
    const int NB = (N + 1023) / 1024;

    prep_w_kernel<<<256, TB, 0, stream>>>(W0, W1, W2, wsp);
    init_kernel<<<2048, TB, 0, stream>>>(x, zp, deg, N);
    degree_kernel<<<1024, TB, 0, stream>>>(col, deg, E);
    scan_part_kernel<<<NB, 1024, 0, stream>>>(deg, off, bsum, N);
    scan_tops_kernel<<<1, 64, 0, stream>>>(bsum, btot, NB);
    scan_add_kernel<<<NB, 1024, 0, stream>>>(off, cur, btot, N, NB);
    scatter_kernel<<<1024, TB, 0, stream>>>(row, col, deg, cur, meta, E);

    int spmm_blocks = (N * 64 + TB - 1) / TB;
    for (int hop = 1; hop <= 3; ++hop) {
        const unsigned* zin = zp + (hop - 1) * NCH;
        unsigned* zout      = zp + hop * NCH;
        spmm_csr_kernel<<<spmm_blocks, TB, 0, stream>>>(off, meta, zin, zout, N);
    }

    int gblocks = (N + 127) / 128;                        // 391
    dim3 g256(gblocks, 2);
    gemm256_kernel<<<g256, TB, 0, stream>>>(zp, wsp,          wsp + 65536,  b0, hp, N);
    gemm256_kernel<<<g256, TB, 0, stream>>>(hp, wsp + 131072, wsp + 196608, b1, zp, N);
    gemm64_kernel<<<gblocks, TB, 0, stream>>>(zp, wsp + 262144, wsp + 278528, b2, out, N);
}

// Round 5
// 386.033 us; speedup vs baseline: 2.3419x; 1.1150x over previous
//
#include <hip/hip_runtime.h>

// SIGN: N=50000, E=800000, CIN=64, HOPS=3, HID=256, COUT=64
// z PACKED: u32 = (bf16_hi << 16) | bf16_lo, value = hi + lo (~fp32 to 2^-18).
// SPMM: CSR-by-destination, no float atomics.
// MLP: split-bf16 MFMA, 2-phase double-buffered global_load_lds pipeline.

#define ZW 256
#define NCH 64

typedef __attribute__((ext_vector_type(8))) __bf16 bf16x8;
typedef __attribute__((ext_vector_type(4))) float f32x4;

__device__ __forceinline__ unsigned f2bf(float f) {
    unsigned x = __float_as_uint(f);
    return (x + 0x7fffu + ((x >> 16) & 1u)) >> 16;   // RNE, finite inputs
}
__device__ __forceinline__ unsigned pack_split(float v) {
    unsigned hb = f2bf(v);
    float hf = __uint_as_float(hb << 16);
    unsigned lb = f2bf(v - hf);
    return (hb << 16) | lb;
}
__device__ __forceinline__ float unpack_f(unsigned u) {
    return __uint_as_float(u & 0xffff0000u) + __uint_as_float(u << 16);
}

// async global->LDS, 16B per lane; LDS dest = uniform base + lane*16 (linear).
__device__ __forceinline__ void gload16(const void* g, void* l) {
    __builtin_amdgcn_global_load_lds(
        (const __attribute__((address_space(1))) unsigned*)g,
        (__attribute__((address_space(3))) unsigned*)l, 16, 0, 0);
}

// ---------------- prologue ----------------

__global__ void init_kernel(const float* __restrict__ x, unsigned* __restrict__ zp,
                            int* __restrict__ deg, int N) {
    int stride = gridDim.x * blockDim.x;
    int total4 = N * 16;
    for (int idx = blockIdx.x * blockDim.x + threadIdx.x; idx < total4; idx += stride) {
        int n = idx >> 4, c4 = idx & 15;
        float4 v = *reinterpret_cast<const float4*>(x + (size_t)n * NCH + c4 * 4);
        uint4 o;
        o.x = pack_split(v.x); o.y = pack_split(v.y);
        o.z = pack_split(v.z); o.w = pack_split(v.w);
        *reinterpret_cast<uint4*>(zp + (size_t)n * ZW + c4 * 4) = o;
    }
    for (int idx = blockIdx.x * blockDim.x + threadIdx.x; idx < N; idx += stride)
        deg[idx] = 0;
}

__global__ void degree_kernel(const int* __restrict__ col, int* __restrict__ deg, int E) {
    int stride = gridDim.x * blockDim.x;
    for (int e = blockIdx.x * blockDim.x + threadIdx.x; e < E; e += stride)
        atomicAdd(&deg[col[e]], 1);
}

__global__ __launch_bounds__(1024) void scan_part_kernel(const int* __restrict__ deg,
                                                         int* __restrict__ off,
                                                         int* __restrict__ bsum, int N) {
    __shared__ int smem[1024];
    int tid = threadIdx.x;
    int i = blockIdx.x * 1024 + tid;
    int v = (i < N) ? deg[i] : 0;
    smem[tid] = v;
    __syncthreads();
    for (int o = 1; o < 1024; o <<= 1) {
        int t = (tid >= o) ? smem[tid - o] : 0;
        __syncthreads();
        smem[tid] += t;
        __syncthreads();
    }
    if (i < N) off[i] = smem[tid] - v;
    if (tid == 1023) bsum[blockIdx.x] = smem[1023];
}

__global__ void scan_tops_kernel(const int* __restrict__ bsum, int* __restrict__ btot, int nb) {
    int lane = threadIdx.x;
    int v = (lane < nb) ? bsum[lane] : 0;
    int incl = v;
    for (int o = 1; o < 64; o <<= 1) {
        int t = __shfl_up(incl, o);
        if (lane >= o) incl += t;
    }
    if (lane < nb) btot[lane] = incl - v;
    if (lane == 63) btot[nb] = incl;
}

__global__ __launch_bounds__(1024) void scan_add_kernel(int* __restrict__ off,
                                                        int* __restrict__ cur,
                                                        const int* __restrict__ btot,
                                                        int N, int nb) {
    int i = blockIdx.x * 1024 + threadIdx.x;
    if (i < N) {
        int o = off[i] + btot[blockIdx.x];
        off[i] = o;
        cur[i] = o;
    }
    if (i == 0) off[N] = btot[nb];
}

__global__ void scatter_kernel(const int* __restrict__ row, const int* __restrict__ col,
                               const int* __restrict__ deg, int* __restrict__ cursor,
                               int2* __restrict__ meta, int E) {
    int stride = gridDim.x * blockDim.x;
    for (int e = blockIdx.x * blockDim.x + threadIdx.x; e < E; e += stride) {
        int r = row[e];
        int c = col[e];
        int dc = deg[c];
        int dr = deg[r];
        float v = 0.0f;
        if (dc > 0 && dr > 0) v = rsqrtf((float)(dc * dr));
        int pos = atomicAdd(&cursor[c], 1);
        meta[pos] = make_int2(r, __float_as_int(v));
    }
}

// One wave per destination node; lane = channel. 4-wide unroll for gather ILP.
__global__ void spmm_csr_kernel(const int* __restrict__ offsets, const int2* __restrict__ meta,
                                const unsigned* __restrict__ zin, unsigned* __restrict__ zout,
                                int N) {
    int lane = threadIdx.x & 63;
    int wave = (blockIdx.x * blockDim.x + threadIdx.x) >> 6;
    if (wave >= N) return;
    int start = offsets[wave];
    int end   = offsets[wave + 1];
    float acc = 0.0f;
    int j = start;
    for (; j + 4 <= end; j += 4) {
        int2 m0 = meta[j];
        int2 m1 = meta[j + 1];
        int2 m2 = meta[j + 2];
        int2 m3 = meta[j + 3];
        float h0 = unpack_f(zin[(size_t)m0.x * ZW + lane]);
        float h1 = unpack_f(zin[(size_t)m1.x * ZW + lane]);
        float h2 = unpack_f(zin[(size_t)m2.x * ZW + lane]);
        float h3 = unpack_f(zin[(size_t)m3.x * ZW + lane]);
        acc = fmaf(__int_as_float(m0.y), h0, acc);
        acc = fmaf(__int_as_float(m1.y), h1, acc);
        acc = fmaf(__int_as_float(m2.y), h2, acc);
        acc = fmaf(__int_as_float(m3.y), h3, acc);
    }
    for (; j + 2 <= end; j += 2) {
        int2 m0 = meta[j];
        int2 m1 = meta[j + 1];
        float h0 = unpack_f(zin[(size_t)m0.x * ZW + lane]);
        float h1 = unpack_f(zin[(size_t)m1.x * ZW + lane]);
        acc = fmaf(__int_as_float(m0.y), h0, acc);
        acc = fmaf(__int_as_float(m1.y), h1, acc);
    }
    if (j < end) {
        int2 m0 = meta[j];
        acc = fmaf(__int_as_float(m0.y), unpack_f(zin[(size_t)m0.x * ZW + lane]), acc);
    }
    zout[(size_t)wave * ZW + lane] = pack_split(acc);
}

// Split + transpose weights: W[k][n] fp32 -> Wh/Wl[n][k] bf16 (ushort bits).
__global__ void prep_w_kernel(const float* __restrict__ W0, const float* __restrict__ W1,
                              const float* __restrict__ W2, unsigned short* __restrict__ ws) {
    int idx = blockIdx.x * blockDim.x + threadIdx.x;
    if (idx >= 65536) return;
    int n = idx >> 8, k = idx & 255;
    unsigned p0 = pack_split(W0[(size_t)k * 256 + n]);
    ws[idx]          = (unsigned short)(p0 >> 16);
    ws[65536 + idx]  = (unsigned short)(p0 & 0xffff);
    unsigned p1 = pack_split(W1[(size_t)k * 256 + n]);
    ws[131072 + idx] = (unsigned short)(p1 >> 16);
    ws[196608 + idx] = (unsigned short)(p1 & 0xffff);
    if (idx < 16384) {
        int n2 = idx >> 8, k2 = idx & 255;       // n2 in [0,64)
        unsigned p2 = pack_split(W2[(size_t)k2 * 64 + n2]);
        ws[262144 + idx] = (unsigned short)(p2 >> 16);
        ws[278528 + idx] = (unsigned short)(p2 & 0xffff);
    }
}

// ---------- GEMM 1/2: Cp[M,256] = relu(Ap@W + b), packed in/out ----------
// BM=128, BN=128, BK=32; 4 waves (2x2), wave tile 64x64; double-buffered gload_lds.
// A in LDS as packed u32 [128][32], 16B-chunk swizzle c^(r&7).
// B planes [128][32] bf16, swizzle c^((n>>1)&3). Linear dest + pre-swizzled source.
__global__ __launch_bounds__(256, 2) void gemm256_kernel(
        const unsigned* __restrict__ Ap, const unsigned short* __restrict__ Wh,
        const unsigned short* __restrict__ Wl, const float* __restrict__ bias,
        unsigned* __restrict__ Cp, int M) {
    __shared__ unsigned Apl[2 * 128 * 32];          // 32 KB
    __shared__ unsigned short Bhl[2 * 128 * 32];    // 16 KB
    __shared__ unsigned short Bll[2 * 128 * 32];    // 16 KB

    int tid = threadIdx.x;
    int lane = tid & 63;
    int wid = tid >> 6;
    int wr = wid >> 1, wc = wid & 1;
    int bm = blockIdx.x * 128;
    int bn = blockIdx.y * 128;
    int l15 = lane & 15, kg = lane >> 4;

    f32x4 acc[4][4] = {};

    auto STAGE = [&](int buf, int k0) {
        unsigned* Ab = Apl + buf * (128 * 32);
        unsigned short* Bhb = Bhl + buf * (128 * 32);
        unsigned short* Blb = Bll + buf * (128 * 32);
#pragma unroll
        for (int i = 0; i < 4; ++i) {
            int s = (wid * 4 + i) * 64 + lane;       // chunk-slot 0..1023
            int r = s >> 3, cp = s & 7;
            int cl = cp ^ (r & 7);
            int grow = bm + r; if (grow >= M) grow = M - 1;
            gload16(Ap + (size_t)grow * 256 + k0 + cl * 4, Ab + (wid * 4 + i) * 256);
        }
#pragma unroll
        for (int i = 0; i < 2; ++i) {
            int s = (wid * 2 + i) * 64 + lane;       // chunk-slot 0..511
            int n = s >> 2, cp = s & 3;
            int cl = cp ^ ((n >> 1) & 3);
            size_t goff = (size_t)(bn + n) * 256 + k0 + cl * 8;
            gload16(Wh + goff, Bhb + (wid * 2 + i) * 512);
            gload16(Wl + goff, Blb + (wid * 2 + i) * 512);
        }
    };

    auto COMPUTE = [&](int buf) {
        const unsigned* Ab = Apl + buf * (128 * 32);
        const unsigned short* Bhb = Bhl + buf * (128 * 32);
        const unsigned short* Blb = Bll + buf * (128 * 32);
        bf16x8 bh[4], bl[4];
#pragma unroll
        for (int n4 = 0; n4 < 4; ++n4) {
            int nn = wc * 64 + n4 * 16 + l15;
            int c = kg ^ ((nn >> 1) & 3);
            bh[n4] = *reinterpret_cast<const bf16x8*>(&Bhb[nn * 32 + c * 8]);
            bl[n4] = *reinterpret_cast<const bf16x8*>(&Blb[nn * 32 + c * 8]);
        }
#pragma unroll
        for (int m = 0; m < 4; ++m) {
            int r = wr * 64 + m * 16 + l15;
            int c0 = (2 * kg) ^ (r & 7);
            int c1 = (2 * kg + 1) ^ (r & 7);
            uint4 q0 = *reinterpret_cast<const uint4*>(&Ab[r * 32 + c0 * 4]);
            uint4 q1 = *reinterpret_cast<const uint4*>(&Ab[r * 32 + c1 * 4]);
            union { bf16x8 v; unsigned short s[8]; } ah, al;
            ah.s[0] = (unsigned short)(q0.x >> 16); al.s[0] = (unsigned short)q0.x;
            ah.s[1] = (unsigned short)(q0.y >> 16); al.s[1] = (unsigned short)q0.y;
            ah.s[2] = (unsigned short)(q0.z >> 16); al.s[2] = (unsigned short)q0.z;
            ah.s[3] = (unsigned short)(q0.w >> 16); al.s[3] = (unsigned short)q0.w;
            ah.s[4] = (unsigned short)(q1.x >> 16); al.s[4] = (unsigned short)q1.x;
            ah.s[5] = (unsigned short)(q1.y >> 16); al.s[5] = (unsigned short)q1.y;
            ah.s[6] = (unsigned short)(q1.z >> 16); al.s[6] = (unsigned short)q1.z;
            ah.s[7] = (unsigned short)(q1.w >> 16); al.s[7] = (unsigned short)q1.w;
#pragma unroll
            for (int n4 = 0; n4 < 4; ++n4) {
                acc[m][n4] = __builtin_amdgcn_mfma_f32_16x16x32_bf16(ah.v, bh[n4], acc[m][n4], 0, 0, 0);
                acc[m][n4] = __builtin_amdgcn_mfma_f32_16x16x32_bf16(ah.v, bl[n4], acc[m][n4], 0, 0, 0);
                acc[m][n4] = __builtin_amdgcn_mfma_f32_16x16x32_bf16(al.v, bh[n4], acc[m][n4], 0, 0, 0);
            }
        }
    };

    STAGE(0, 0);
    __syncthreads();
#pragma unroll
    for (int t = 0; t < 8; ++t) {
        if (t < 7) STAGE((t + 1) & 1, (t + 1) * 32);
        COMPUTE(t & 1);
        __syncthreads();
    }

    // epilogue: C row = kg*4 + reg, col = l15 within each 16x16 frag [m89]
#pragma unroll
    for (int n4 = 0; n4 < 4; ++n4) {
        int col = bn + wc * 64 + n4 * 16 + l15;
        float bv = bias[col];
#pragma unroll
        for (int m = 0; m < 4; ++m) {
#pragma unroll
            for (int rr = 0; rr < 4; ++rr) {
                int row = bm + wr * 64 + m * 16 + kg * 4 + rr;
                if (row < M) {
                    float v = fmaxf(acc[m][n4][rr] + bv, 0.0f);
                    Cp[(size_t)row * 256 + col] = pack_split(v);
                }
            }
        }
    }
}

// ---------- GEMM 3: out[M,64] = Ap@W2 + b2 (fp32 out) ----------
// BM=128 (4 waves stacked, wave tile 32x64), BN=64; same pipeline.
__global__ __launch_bounds__(256, 3) void gemm64_kernel(
        const unsigned* __restrict__ Ap, const unsigned short* __restrict__ Wh,
        const unsigned short* __restrict__ Wl, const float* __restrict__ bias,
        float* __restrict__ out, int M) {
    __shared__ unsigned Apl[2 * 128 * 32];          // 32 KB
    __shared__ unsigned short Bhl[2 * 64 * 32];     // 8 KB
    __shared__ unsigned short Bll[2 * 64 * 32];     // 8 KB

    int tid = threadIdx.x;
    int lane = tid & 63;
    int wid = tid >> 6;
    int bm = blockIdx.x * 128;
    int l15 = lane & 15, kg = lane >> 4;

    f32x4 acc[2][4] = {};

    auto STAGE = [&](int buf, int k0) {
        unsigned* Ab = Apl + buf * (128 * 32);
        unsigned short* Bhb = Bhl + buf * (64 * 32);
        unsigned short* Blb = Bll + buf * (64 * 32);
#pragma unroll
        for (int i = 0; i < 4; ++i) {
            int s = (wid * 4 + i) * 64 + lane;
            int r = s >> 3, cp = s & 7;
            int cl = cp ^ (r & 7);
            int grow = bm + r; if (grow >= M) grow = M - 1;
            gload16(Ap + (size_t)grow * 256 + k0 + cl * 4, Ab + (wid * 4 + i) * 256);
        }
        {
            int s = wid * 64 + lane;                 // chunk-slot 0..255
            int n = s >> 2, cp = s & 3;
            int cl = cp ^ ((n >> 1) & 3);
            size_t goff = (size_t)n * 256 + k0 + cl * 8;
            gload16(Wh + goff, Bhb + wid * 512);
            gload16(Wl + goff, Blb + wid * 512);
        }
    };

    auto COMPUTE = [&](int buf) {
        const unsigned* Ab = Apl + buf * (128 * 32);
        const unsigned short* Bhb = Bhl + buf * (64 * 32);
        const unsigned short* Blb = Bll + buf * (64 * 32);
        bf16x8 bh[4], bl[4];
#pragma unroll
        for (int n4 = 0; n4 < 4; ++n4) {
            int nn = n4 * 16 + l15;
            int c = kg ^ ((nn >> 1) & 3);
            bh[n4] = *reinterpret_cast<const bf16x8*>(&Bhb[nn * 32 + c * 8]);
            bl[n4] = *reinterpret_cast<const bf16x8*>(&Blb[nn * 32 + c * 8]);
        }
#pragma unroll
        for (int m = 0; m < 2; ++m) {
            int r = wid * 32 + m * 16 + l15;
            int c0 = (2 * kg) ^ (r & 7);
            int c1 = (2 * kg + 1) ^ (r & 7);
            uint4 q0 = *reinterpret_cast<const uint4*>(&Ab[r * 32 + c0 * 4]);
            uint4 q1 = *reinterpret_cast<const uint4*>(&Ab[r * 32 + c1 * 4]);
            union { bf16x8 v; unsigned short s[8]; } ah, al;
            ah.s[0] = (unsigned short)(q0.x >> 16); al.s[0] = (unsigned short)q0.x;
            ah.s[1] = (unsigned short)(q0.y >> 16); al.s[1] = (unsigned short)q0.y;
            ah.s[2] = (unsigned short)(q0.z >> 16); al.s[2] = (unsigned short)q0.z;
            ah.s[3] = (unsigned short)(q0.w >> 16); al.s[3] = (unsigned short)q0.w;
            ah.s[4] = (unsigned short)(q1.x >> 16); al.s[4] = (unsigned short)q1.x;
            ah.s[5] = (unsigned short)(q1.y >> 16); al.s[5] = (unsigned short)q1.y;
            ah.s[6] = (unsigned short)(q1.z >> 16); al.s[6] = (unsigned short)q1.z;
            ah.s[7] = (unsigned short)(q1.w >> 16); al.s[7] = (unsigned short)q1.w;
#pragma unroll
            for (int n4 = 0; n4 < 4; ++n4) {
                acc[m][n4] = __builtin_amdgcn_mfma_f32_16x16x32_bf16(ah.v, bh[n4], acc[m][n4], 0, 0, 0);
                acc[m][n4] = __builtin_amdgcn_mfma_f32_16x16x32_bf16(ah.v, bl[n4], acc[m][n4], 0, 0, 0);
                acc[m][n4] = __builtin_amdgcn_mfma_f32_16x16x32_bf16(al.v, bh[n4], acc[m][n4], 0, 0, 0);
            }
        }
    };

    STAGE(0, 0);
    __syncthreads();
#pragma unroll
    for (int t = 0; t < 8; ++t) {
        if (t < 7) STAGE((t + 1) & 1, (t + 1) * 32);
        COMPUTE(t & 1);
        __syncthreads();
    }

#pragma unroll
    for (int n4 = 0; n4 < 4; ++n4) {
        int col = n4 * 16 + l15;
        float bv = bias[col];
#pragma unroll
        for (int m = 0; m < 2; ++m) {
#pragma unroll
            for (int rr = 0; rr < 4; ++rr) {
                int row = bm + wid * 32 + m * 16 + kg * 4 + rr;
                if (row < M) out[(size_t)row * 64 + col] = acc[m][n4][rr] + bv;
            }
        }
    }
}

extern "C" void kernel_launch(void* const* d_in, const int* in_sizes, int n_in,
                              void* d_out, int out_size, void* d_ws, size_t ws_size,
                              hipStream_t stream) {
    const float* x  = (const float*)d_in[0];
    const int* ei   = (const int*)d_in[1];
    const float* W0 = (const float*)d_in[2];
    const float* b0 = (const float*)d_in[3];
    const float* W1 = (const float*)d_in[4];
    const float* b1 = (const float*)d_in[5];
    const float* W2 = (const float*)d_in[6];
    const float* b2 = (const float*)d_in[7];
    float* out = (float*)d_out;

    const int N = in_sizes[0] / NCH;      // 50000
    const int E = in_sizes[1] / 2;        // 800000
    const int* row = ei;
    const int* col = ei + E;

    // workspace (wsp placed before int arrays to keep 16B alignment for gload_lds)
    unsigned* zp = (unsigned*)d_ws;                       // N*256 u32
    unsigned* hp = zp + (size_t)N * ZW;                   // N*256 u32 (meta overlay)
    unsigned short* wsp = (unsigned short*)(hp + (size_t)N * ZW);  // 294912 ushorts
    int* deg  = (int*)(wsp + 294912);                     // N
    int* off  = deg + N;                                  // N+1
    int* cur  = off + N + 1;                              // N
    int* bsum = cur + N;                                  // 64
    int* btot = bsum + 64;                                // 80
    int2* meta = (int2*)hp;                               // overlays hp (disjoint lifetime)

    const int TB = 256;
    const int NB = (N + 1023) / 1024;

    prep_w_kernel<<<256, TB, 0, stream>>>(W0, W1, W2, wsp);
    init_kernel<<<2048, TB, 0, stream>>>(x, zp, deg, N);
    degree_kernel<<<1024, TB, 0, stream>>>(col, deg, E);
    scan_part_kernel<<<NB, 1024, 0, stream>>>(deg, off, bsum, N);
    scan_tops_kernel<<<1, 64, 0, stream>>>(bsum, btot, NB);
    scan_add_kernel<<<NB, 1024, 0, stream>>>(off, cur, btot, N, NB);
    scatter_kernel<<<1024, TB, 0, stream>>>(row, col, deg, cur, meta, E);

    int spmm_blocks = (N * 64 + TB - 1) / TB;
    for (int hop = 1; hop <= 3; ++hop) {
        const unsigned* zin = zp + (hop - 1) * NCH;
        unsigned* zout      = zp + hop * NCH;
        spmm_csr_kernel<<<spmm_blocks, TB, 0, stream>>>(off, meta, zin, zout, N);
    }

    int gblocks = (N + 127) / 128;                        // 391
    dim3 g256(gblocks, 2);
    gemm256_kernel<<<g256, TB, 0, stream>>>(zp, wsp,          wsp + 65536,  b0, hp, N);
    gemm256_kernel<<<g256, TB, 0, stream>>>(hp, wsp + 131072, wsp + 196608, b1, zp, N);
    gemm64_kernel<<<gblocks, TB, 0, stream>>>(zp, wsp + 262144, wsp + 278528, b2, out, N);
}

// Round 6
// 381.371 us; speedup vs baseline: 2.3705x; 1.0122x over previous
//
#include <hip/hip_runtime.h>

// SIGN: N=50000, E=800000, CIN=64, HOPS=3, HID=256, COUT=64
// z PACKED: u32 = (bf16_hi << 16) | bf16_lo, value = hi + lo (~fp32 to 2^-18).
// SPMM: CSR-by-destination, no float atomics. CSR build: XCD-sliced scatter
// (each blockIdx%8 set owns 1/8 of destinations -> per-XCD L2-local writes).
// MLP: split-bf16 MFMA, 2-phase double-buffered global_load_lds pipeline.

#define ZW 256
#define NCH 64

typedef __attribute__((ext_vector_type(8))) __bf16 bf16x8;
typedef __attribute__((ext_vector_type(4))) float f32x4;

__device__ __forceinline__ unsigned f2bf(float f) {
    unsigned x = __float_as_uint(f);
    return (x + 0x7fffu + ((x >> 16) & 1u)) >> 16;   // RNE, finite inputs
}
__device__ __forceinline__ unsigned pack_split(float v) {
    unsigned hb = f2bf(v);
    float hf = __uint_as_float(hb << 16);
    unsigned lb = f2bf(v - hf);
    return (hb << 16) | lb;
}
__device__ __forceinline__ float unpack_f(unsigned u) {
    return __uint_as_float(u & 0xffff0000u) + __uint_as_float(u << 16);
}

// async global->LDS, 16B per lane; LDS dest = uniform base + lane*16 (linear).
__device__ __forceinline__ void gload16(const void* g, void* l) {
    __builtin_amdgcn_global_load_lds(
        (const __attribute__((address_space(1))) unsigned*)g,
        (__attribute__((address_space(3))) unsigned*)l, 16, 0, 0);
}

// ---------------- prologue ----------------

__global__ void init_kernel(const float* __restrict__ x, unsigned* __restrict__ zp,
                            int* __restrict__ deg, int N) {
    int stride = gridDim.x * blockDim.x;
    int total4 = N * 16;
    for (int idx = blockIdx.x * blockDim.x + threadIdx.x; idx < total4; idx += stride) {
        int n = idx >> 4, c4 = idx & 15;
        float4 v = *reinterpret_cast<const float4*>(x + (size_t)n * NCH + c4 * 4);
        uint4 o;
        o.x = pack_split(v.x); o.y = pack_split(v.y);
        o.z = pack_split(v.z); o.w = pack_split(v.w);
        *reinterpret_cast<uint4*>(zp + (size_t)n * ZW + c4 * 4) = o;
    }
    for (int idx = blockIdx.x * blockDim.x + threadIdx.x; idx < N; idx += stride)
        deg[idx] = 0;
}

// XCD-sliced: block-set (blockIdx%8 == s) handles dests in slice s only.
// Each XCD's L2 then holds only its 1/8 of deg -> atomic lines stay resident.
__global__ void degree_kernel(const int* __restrict__ col, int* __restrict__ deg,
                              int E, int N) {
    int slice = blockIdx.x & 7;
    int g = blockIdx.x >> 3;
    int G = gridDim.x >> 3;
    int sliceN = (N + 7) >> 3;
    int lo = slice * sliceN;
    int hi = lo + sliceN; if (hi > N) hi = N;
    int stride = G * blockDim.x;
    for (int e = g * blockDim.x + threadIdx.x; e < E; e += stride) {
        int c = col[e];
        if (c >= lo && c < hi) atomicAdd(&deg[c], 1);
    }
}

__global__ __launch_bounds__(1024) void scan_part_kernel(const int* __restrict__ deg,
                                                         int* __restrict__ off,
                                                         int* __restrict__ bsum, int N) {
    __shared__ int smem[1024];
    int tid = threadIdx.x;
    int i = blockIdx.x * 1024 + tid;
    int v = (i < N) ? deg[i] : 0;
    smem[tid] = v;
    __syncthreads();
    for (int o = 1; o < 1024; o <<= 1) {
        int t = (tid >= o) ? smem[tid - o] : 0;
        __syncthreads();
        smem[tid] += t;
        __syncthreads();
    }
    if (i < N) off[i] = smem[tid] - v;
    if (tid == 1023) bsum[blockIdx.x] = smem[1023];
}

__global__ void scan_tops_kernel(const int* __restrict__ bsum, int* __restrict__ btot, int nb) {
    int lane = threadIdx.x;
    int v = (lane < nb) ? bsum[lane] : 0;
    int incl = v;
    for (int o = 1; o < 64; o <<= 1) {
        int t = __shfl_up(incl, o);
        if (lane >= o) incl += t;
    }
    if (lane < nb) btot[lane] = incl - v;
    if (lane == 63) btot[nb] = incl;
}

__global__ __launch_bounds__(1024) void scan_add_kernel(int* __restrict__ off,
                                                        int* __restrict__ cur,
                                                        const int* __restrict__ btot,
                                                        int N, int nb) {
    int i = blockIdx.x * 1024 + threadIdx.x;
    if (i < N) {
        int o = off[i] + btot[blockIdx.x];
        off[i] = o;
        cur[i] = o;
    }
    if (i == 0) off[N] = btot[nb];
}

// XCD-sliced scatter: slice-set s scatters only edges with col in slice s.
// meta slice (0.8 MB) stays in that XCD's L2 -> full-line write-back (~6.4 MB
// total instead of E*64B = 51 MB of partial-line evictions).
__global__ void scatter_kernel(const int* __restrict__ row, const int* __restrict__ col,
                               const int* __restrict__ deg, int* __restrict__ cursor,
                               int2* __restrict__ meta, int E, int N) {
    int slice = blockIdx.x & 7;
    int g = blockIdx.x >> 3;
    int G = gridDim.x >> 3;
    int sliceN = (N + 7) >> 3;
    int lo = slice * sliceN;
    int hi = lo + sliceN; if (hi > N) hi = N;
    int stride = G * blockDim.x;
    for (int e = g * blockDim.x + threadIdx.x; e < E; e += stride) {
        int c = col[e];
        if (c >= lo && c < hi) {
            int r = row[e];
            int dc = deg[c];
            int dr = deg[r];
            float v = 0.0f;
            if (dc > 0 && dr > 0) v = rsqrtf((float)dc * (float)dr);
            int pos = atomicAdd(&cursor[c], 1);
            meta[pos] = make_int2(r, __float_as_int(v));
        }
    }
}

// One wave per destination node; lane = channel. 4-wide unroll for gather ILP.
__global__ void spmm_csr_kernel(const int* __restrict__ offsets, const int2* __restrict__ meta,
                                const unsigned* __restrict__ zin, unsigned* __restrict__ zout,
                                int N) {
    int lane = threadIdx.x & 63;
    int wave = (blockIdx.x * blockDim.x + threadIdx.x) >> 6;
    if (wave >= N) return;
    int start = offsets[wave];
    int end   = offsets[wave + 1];
    float acc = 0.0f;
    int j = start;
    for (; j + 4 <= end; j += 4) {
        int2 m0 = meta[j];
        int2 m1 = meta[j + 1];
        int2 m2 = meta[j + 2];
        int2 m3 = meta[j + 3];
        float h0 = unpack_f(zin[(size_t)m0.x * ZW + lane]);
        float h1 = unpack_f(zin[(size_t)m1.x * ZW + lane]);
        float h2 = unpack_f(zin[(size_t)m2.x * ZW + lane]);
        float h3 = unpack_f(zin[(size_t)m3.x * ZW + lane]);
        acc = fmaf(__int_as_float(m0.y), h0, acc);
        acc = fmaf(__int_as_float(m1.y), h1, acc);
        acc = fmaf(__int_as_float(m2.y), h2, acc);
        acc = fmaf(__int_as_float(m3.y), h3, acc);
    }
    for (; j + 2 <= end; j += 2) {
        int2 m0 = meta[j];
        int2 m1 = meta[j + 1];
        float h0 = unpack_f(zin[(size_t)m0.x * ZW + lane]);
        float h1 = unpack_f(zin[(size_t)m1.x * ZW + lane]);
        acc = fmaf(__int_as_float(m0.y), h0, acc);
        acc = fmaf(__int_as_float(m1.y), h1, acc);
    }
    if (j < end) {
        int2 m0 = meta[j];
        acc = fmaf(__int_as_float(m0.y), unpack_f(zin[(size_t)m0.x * ZW + lane]), acc);
    }
    zout[(size_t)wave * ZW + lane] = pack_split(acc);
}

// Split + transpose weights: W[k][n] fp32 -> Wh/Wl[n][k] bf16 (ushort bits).
__global__ void prep_w_kernel(const float* __restrict__ W0, const float* __restrict__ W1,
                              const float* __restrict__ W2, unsigned short* __restrict__ ws) {
    int idx = blockIdx.x * blockDim.x + threadIdx.x;
    if (idx >= 65536) return;
    int n = idx >> 8, k = idx & 255;
    unsigned p0 = pack_split(W0[(size_t)k * 256 + n]);
    ws[idx]          = (unsigned short)(p0 >> 16);
    ws[65536 + idx]  = (unsigned short)(p0 & 0xffff);
    unsigned p1 = pack_split(W1[(size_t)k * 256 + n]);
    ws[131072 + idx] = (unsigned short)(p1 >> 16);
    ws[196608 + idx] = (unsigned short)(p1 & 0xffff);
    if (idx < 16384) {
        int n2 = idx >> 8, k2 = idx & 255;       // n2 in [0,64)
        unsigned p2 = pack_split(W2[(size_t)k2 * 64 + n2]);
        ws[262144 + idx] = (unsigned short)(p2 >> 16);
        ws[278528 + idx] = (unsigned short)(p2 & 0xffff);
    }
}

// ---------- GEMM 1/2: Cp[M,256] = relu(Ap@W + b), packed in/out ----------
// BM=128, BN=128, BK=32; 4 waves (2x2), wave tile 64x64; double-buffered gload_lds.
__global__ __launch_bounds__(256, 2) void gemm256_kernel(
        const unsigned* __restrict__ Ap, const unsigned short* __restrict__ Wh,
        const unsigned short* __restrict__ Wl, const float* __restrict__ bias,
        unsigned* __restrict__ Cp, int M) {
    __shared__ unsigned Apl[2 * 128 * 32];          // 32 KB
    __shared__ unsigned short Bhl[2 * 128 * 32];    // 16 KB
    __shared__ unsigned short Bll[2 * 128 * 32];    // 16 KB

    int tid = threadIdx.x;
    int lane = tid & 63;
    int wid = tid >> 6;
    int wr = wid >> 1, wc = wid & 1;
    int bm = blockIdx.x * 128;
    int bn = blockIdx.y * 128;
    int l15 = lane & 15, kg = lane >> 4;

    f32x4 acc[4][4] = {};

    auto STAGE = [&](int buf, int k0) {
        unsigned* Ab = Apl + buf * (128 * 32);
        unsigned short* Bhb = Bhl + buf * (128 * 32);
        unsigned short* Blb = Bll + buf * (128 * 32);
#pragma unroll
        for (int i = 0; i < 4; ++i) {
            int s = (wid * 4 + i) * 64 + lane;       // chunk-slot 0..1023
            int r = s >> 3, cp = s & 7;
            int cl = cp ^ (r & 7);
            int grow = bm + r; if (grow >= M) grow = M - 1;
            gload16(Ap + (size_t)grow * 256 + k0 + cl * 4, Ab + (wid * 4 + i) * 256);
        }
#pragma unroll
        for (int i = 0; i < 2; ++i) {
            int s = (wid * 2 + i) * 64 + lane;       // chunk-slot 0..511
            int n = s >> 2, cp = s & 3;
            int cl = cp ^ ((n >> 1) & 3);
            size_t goff = (size_t)(bn + n) * 256 + k0 + cl * 8;
            gload16(Wh + goff, Bhb + (wid * 2 + i) * 512);
            gload16(Wl + goff, Blb + (wid * 2 + i) * 512);
        }
    };

    auto COMPUTE = [&](int buf) {
        const unsigned* Ab = Apl + buf * (128 * 32);
        const unsigned short* Bhb = Bhl + buf * (128 * 32);
        const unsigned short* Blb = Bll + buf * (128 * 32);
        bf16x8 bh[4], bl[4];
#pragma unroll
        for (int n4 = 0; n4 < 4; ++n4) {
            int nn = wc * 64 + n4 * 16 + l15;
            int c = kg ^ ((nn >> 1) & 3);
            bh[n4] = *reinterpret_cast<const bf16x8*>(&Bhb[nn * 32 + c * 8]);
            bl[n4] = *reinterpret_cast<const bf16x8*>(&Blb[nn * 32 + c * 8]);
        }
#pragma unroll
        for (int m = 0; m < 4; ++m) {
            int r = wr * 64 + m * 16 + l15;
            int c0 = (2 * kg) ^ (r & 7);
            int c1 = (2 * kg + 1) ^ (r & 7);
            uint4 q0 = *reinterpret_cast<const uint4*>(&Ab[r * 32 + c0 * 4]);
            uint4 q1 = *reinterpret_cast<const uint4*>(&Ab[r * 32 + c1 * 4]);
            union { bf16x8 v; unsigned short s[8]; } ah, al;
            ah.s[0] = (unsigned short)(q0.x >> 16); al.s[0] = (unsigned short)q0.x;
            ah.s[1] = (unsigned short)(q0.y >> 16); al.s[1] = (unsigned short)q0.y;
            ah.s[2] = (unsigned short)(q0.z >> 16); al.s[2] = (unsigned short)q0.z;
            ah.s[3] = (unsigned short)(q0.w >> 16); al.s[3] = (unsigned short)q0.w;
            ah.s[4] = (unsigned short)(q1.x >> 16); al.s[4] = (unsigned short)q1.x;
            ah.s[5] = (unsigned short)(q1.y >> 16); al.s[5] = (unsigned short)q1.y;
            ah.s[6] = (unsigned short)(q1.z >> 16); al.s[6] = (unsigned short)q1.z;
            ah.s[7] = (unsigned short)(q1.w >> 16); al.s[7] = (unsigned short)q1.w;
#pragma unroll
            for (int n4 = 0; n4 < 4; ++n4) {
                acc[m][n4] = __builtin_amdgcn_mfma_f32_16x16x32_bf16(ah.v, bh[n4], acc[m][n4], 0, 0, 0);
                acc[m][n4] = __builtin_amdgcn_mfma_f32_16x16x32_bf16(ah.v, bl[n4], acc[m][n4], 0, 0, 0);
                acc[m][n4] = __builtin_amdgcn_mfma_f32_16x16x32_bf16(al.v, bh[n4], acc[m][n4], 0, 0, 0);
            }
        }
    };

    STAGE(0, 0);
    __syncthreads();
#pragma unroll
    for (int t = 0; t < 8; ++t) {
        if (t < 7) STAGE((t + 1) & 1, (t + 1) * 32);
        COMPUTE(t & 1);
        __syncthreads();
    }

    // epilogue: C row = kg*4 + reg, col = l15 within each 16x16 frag [m89]
#pragma unroll
    for (int n4 = 0; n4 < 4; ++n4) {
        int col = bn + wc * 64 + n4 * 16 + l15;
        float bv = bias[col];
#pragma unroll
        for (int m = 0; m < 4; ++m) {
#pragma unroll
            for (int rr = 0; rr < 4; ++rr) {
                int row = bm + wr * 64 + m * 16 + kg * 4 + rr;
                if (row < M) {
                    float v = fmaxf(acc[m][n4][rr] + bv, 0.0f);
                    Cp[(size_t)row * 256 + col] = pack_split(v);
                }
            }
        }
    }
}

// ---------- GEMM 3: out[M,64] = Ap@W2 + b2 (fp32 out) ----------
__global__ __launch_bounds__(256, 3) void gemm64_kernel(
        const unsigned* __restrict__ Ap, const unsigned short* __restrict__ Wh,
        const unsigned short* __restrict__ Wl, const float* __restrict__ bias,
        float* __restrict__ out, int M) {
    __shared__ unsigned Apl[2 * 128 * 32];          // 32 KB
    __shared__ unsigned short Bhl[2 * 64 * 32];     // 8 KB
    __shared__ unsigned short Bll[2 * 64 * 32];     // 8 KB

    int tid = threadIdx.x;
    int lane = tid & 63;
    int wid = tid >> 6;
    int bm = blockIdx.x * 128;
    int l15 = lane & 15, kg = lane >> 4;

    f32x4 acc[2][4] = {};

    auto STAGE = [&](int buf, int k0) {
        unsigned* Ab = Apl + buf * (128 * 32);
        unsigned short* Bhb = Bhl + buf * (64 * 32);
        unsigned short* Blb = Bll + buf * (64 * 32);
#pragma unroll
        for (int i = 0; i < 4; ++i) {
            int s = (wid * 4 + i) * 64 + lane;
            int r = s >> 3, cp = s & 7;
            int cl = cp ^ (r & 7);
            int grow = bm + r; if (grow >= M) grow = M - 1;
            gload16(Ap + (size_t)grow * 256 + k0 + cl * 4, Ab + (wid * 4 + i) * 256);
        }
        {
            int s = wid * 64 + lane;                 // chunk-slot 0..255
            int n = s >> 2, cp = s & 3;
            int cl = cp ^ ((n >> 1) & 3);
            size_t goff = (size_t)n * 256 + k0 + cl * 8;
            gload16(Wh + goff, Bhb + wid * 512);
            gload16(Wl + goff, Blb + wid * 512);
        }
    };

    auto COMPUTE = [&](int buf) {
        const unsigned* Ab = Apl + buf * (128 * 32);
        const unsigned short* Bhb = Bhl + buf * (64 * 32);
        const unsigned short* Blb = Bll + buf * (64 * 32);
        bf16x8 bh[4], bl[4];
#pragma unroll
        for (int n4 = 0; n4 < 4; ++n4) {
            int nn = n4 * 16 + l15;
            int c = kg ^ ((nn >> 1) & 3);
            bh[n4] = *reinterpret_cast<const bf16x8*>(&Bhb[nn * 32 + c * 8]);
            bl[n4] = *reinterpret_cast<const bf16x8*>(&Blb[nn * 32 + c * 8]);
        }
#pragma unroll
        for (int m = 0; m < 2; ++m) {
            int r = wid * 32 + m * 16 + l15;
            int c0 = (2 * kg) ^ (r & 7);
            int c1 = (2 * kg + 1) ^ (r & 7);
            uint4 q0 = *reinterpret_cast<const uint4*>(&Ab[r * 32 + c0 * 4]);
            uint4 q1 = *reinterpret_cast<const uint4*>(&Ab[r * 32 + c1 * 4]);
            union { bf16x8 v; unsigned short s[8]; } ah, al;
            ah.s[0] = (unsigned short)(q0.x >> 16); al.s[0] = (unsigned short)q0.x;
            ah.s[1] = (unsigned short)(q0.y >> 16); al.s[1] = (unsigned short)q0.y;
            ah.s[2] = (unsigned short)(q0.z >> 16); al.s[2] = (unsigned short)q0.z;
            ah.s[3] = (unsigned short)(q0.w >> 16); al.s[3] = (unsigned short)q0.w;
            ah.s[4] = (unsigned short)(q1.x >> 16); al.s[4] = (unsigned short)q1.x;
            ah.s[5] = (unsigned short)(q1.y >> 16); al.s[5] = (unsigned short)q1.y;
            ah.s[6] = (unsigned short)(q1.z >> 16); al.s[6] = (unsigned short)q1.z;
            ah.s[7] = (unsigned short)(q1.w >> 16); al.s[7] = (unsigned short)q1.w;
#pragma unroll
            for (int n4 = 0; n4 < 4; ++n4) {
                acc[m][n4] = __builtin_amdgcn_mfma_f32_16x16x32_bf16(ah.v, bh[n4], acc[m][n4], 0, 0, 0);
                acc[m][n4] = __builtin_amdgcn_mfma_f32_16x16x32_bf16(ah.v, bl[n4], acc[m][n4], 0, 0, 0);
                acc[m][n4] = __builtin_amdgcn_mfma_f32_16x16x32_bf16(al.v, bh[n4], acc[m][n4], 0, 0, 0);
            }
        }
    };

    STAGE(0, 0);
    __syncthreads();
#pragma unroll
    for (int t = 0; t < 8; ++t) {
        if (t < 7) STAGE((t + 1) & 1, (t + 1) * 32);
        COMPUTE(t & 1);
        __syncthreads();
    }

#pragma unroll
    for (int n4 = 0; n4 < 4; ++n4) {
        int col = n4 * 16 + l15;
        float bv = bias[col];
#pragma unroll
        for (int m = 0; m < 2; ++m) {
#pragma unroll
            for (int rr = 0; rr < 4; ++rr) {
                int row = bm + wid * 32 + m * 16 + kg * 4 + rr;
                if (row < M) out[(size_t)row * 64 + col] = acc[m][n4][rr] + bv;
            }
        }
    }
}

extern "C" void kernel_launch(void* const* d_in, const int* in_sizes, int n_in,
                              void* d_out, int out_size, void* d_ws, size_t ws_size,
                              hipStream_t stream) {
    const float* x  = (const float*)d_in[0];
    const int* ei   = (const int*)d_in[1];
    const float* W0 = (const float*)d_in[2];
    const float* b0 = (const float*)d_in[3];
    const float* W1 = (const float*)d_in[4];
    const float* b1 = (const float*)d_in[5];
    const float* W2 = (const float*)d_in[6];
    const float* b2 = (const float*)d_in[7];
    float* out = (float*)d_out;

    const int N = in_sizes[0] / NCH;      // 50000
    const int E = in_sizes[1] / 2;        // 800000
    const int* row = ei;
    const int* col = ei + E;

    // workspace
    unsigned* zp = (unsigned*)d_ws;                       // N*256 u32
    unsigned* hp = zp + (size_t)N * ZW;                   // N*256 u32 (meta overlay)
    unsigned short* wsp = (unsigned short*)(hp + (size_t)N * ZW);  // 294912 ushorts
    int* deg  = (int*)(wsp + 294912);                     // N
    int* off  = deg + N;                                  // N+1
    int* cur  = off + N + 1;                              // N
    int* bsum = cur + N;                                  // 64
    int* btot = bsum + 64;                                // 80
    int2* meta = (int2*)hp;                               // overlays hp (disjoint lifetime)

    const int TB = 256;
    const int NB = (N + 1023) / 1024;

    prep_w_kernel<<<256, TB, 0, stream>>>(W0, W1, W2, wsp);
    init_kernel<<<2048, TB, 0, stream>>>(x, zp, deg, N);
    degree_kernel<<<1024, TB, 0, stream>>>(col, deg, E, N);
    scan_part_kernel<<<NB, 1024, 0, stream>>>(deg, off, bsum, N);
    scan_tops_kernel<<<1, 64, 0, stream>>>(bsum, btot, NB);
    scan_add_kernel<<<NB, 1024, 0, stream>>>(off, cur, btot, N, NB);
    scatter_kernel<<<1024, TB, 0, stream>>>(row, col, deg, cur, meta, E, N);

    int spmm_blocks = (N * 64 + TB - 1) / TB;
    for (int hop = 1; hop <= 3; ++hop) {
        const unsigned* zin = zp + (hop - 1) * NCH;
        unsigned* zout      = zp + hop * NCH;
        spmm_csr_kernel<<<spmm_blocks, TB, 0, stream>>>(off, meta, zin, zout, N);
    }

    int gblocks = (N + 127) / 128;                        // 391
    dim3 g256(gblocks, 2);
    gemm256_kernel<<<g256, TB, 0, stream>>>(zp, wsp,          wsp + 65536,  b0, hp, N);
    gemm256_kernel<<<g256, TB, 0, stream>>>(hp, wsp + 131072, wsp + 196608, b1, zp, N);
    gemm64_kernel<<<gblocks, TB, 0, stream>>>(zp, wsp + 262144, wsp + 278528, b2, out, N);
}